// Round 7
// baseline (398.630 us; speedup 1.0000x reference)
//
#include <hip/hip_runtime.h>

// LightGCN propagation, CSR-gather, bf16 intermediates, unified row space.
// R16 (from R15 @284us, agg latency attacks exhausted):
//  - Diagnosis: R12/R14/R15 all ~51-53us at occ 34-54% -> gather capped by
//    per-CU outstanding-miss capacity x L3 latency (~3 TB/s). Stop attacking.
//  - Fixed-capacity partitions (CAP=11264 = item-partition mean 10240 + 10σ):
//    hist + scan kernels DELETED. gcur zero-based; scatter at part*CAP+cur;
//    build_csr reads count from gcur[p]. 2 fewer launches, ~12us less head.
//  - rp -> int2{beg,cnt}: one dwordx2 instead of 2 dependent loads per row
//    (entries now gapped per partition, so explicit cnt needed anyway).
//  - Nontemporal stores for F0/H1/H2/partBuf/entries: consumers are on random
//    XCDs, writer-L2 caching is pure pollution; keep L2 for gather reuse.

#define N_USERS 200000
#define N_ITEMS 100000
#define N_EDGES 1000000
#define DIM 64
#define BATCH 8192
#define NTOT (N_USERS + N_ITEMS)          // 300000 rows
#define NOUT (3 * BATCH)                  // 24576 output rows
#define NPART 293                         // ceil(NTOT / 1024)
#define PLOCAL 1024
#define CAP 11264                         // per-partition record capacity

#define HA 489                            // scatter blocks: 8 edges/thread
#define NUNITS (NTOT * DIM / 8)           // 2.4M 8-float convert units
#define CB ((NUNITS + 1023) / 1024)       // 2344 convert blocks (32 floats/thread)
#define OB (NOUT * 8 / 256)               // 768 out_h0 / add1 blocks (8 floats/thread)
#define AB8 (NTOT / 32)                   // 9375 agg blocks (32 rows/block, 8 lanes/row)
#define FB ((NOUT + 255) / 256)           // 96 flag-scatter blocks

// ext-vector types for __builtin_nontemporal_store (HIP structs not accepted)
typedef int      int2v  __attribute__((ext_vector_type(2)));
typedef unsigned uint2v __attribute__((ext_vector_type(2)));
typedef unsigned uint4v __attribute__((ext_vector_type(4)));

// ---------- bf16 helpers ----------
__device__ __forceinline__ unsigned f2bf(float f) {   // round-to-nearest-even
    unsigned u = __float_as_uint(f);
    return (u + 0x7fffu + ((u >> 16) & 1u)) >> 16;
}
__device__ __forceinline__ uint2 pack4(float4 v) {
    uint2 o;
    o.x = f2bf(v.x) | (f2bf(v.y) << 16);
    o.y = f2bf(v.z) | (f2bf(v.w) << 16);
    return o;
}
__device__ __forceinline__ void fma4(float4& a, uint2 v, float w) {
    a.x += __uint_as_float(v.x << 16) * w;
    a.y += __uint_as_float(v.x & 0xffff0000u) * w;
    a.z += __uint_as_float(v.y << 16) * w;
    a.w += __uint_as_float(v.y & 0xffff0000u) * w;
}
__device__ __forceinline__ int out_bucket(int orow, const int* users,
                                          const int* pos, const int* neg) {
    int seg = orow >> 13;
    int b = orow & (BATCH - 1);
    if (seg == 0) return users[b];
    if (seg == 1) return N_USERS + pos[b];
    return N_USERS + neg[b];
}

// ---------------- B: partition scatter + convert + out_h0 ----------------
// record meta = (bucket & 1023) | (col << 10);  col < 2^19, total 29 bits.
// gcur[p] is ZERO-based (memset); record address = p*CAP + cursor.
__global__ void partition_conv_kernel(const int* __restrict__ eu,
                                      const int* __restrict__ ei,
                                      const float* __restrict__ w,
                                      int* __restrict__ gcur,
                                      uint2* __restrict__ partBuf,
                                      const float4* __restrict__ uf4,
                                      const float4* __restrict__ if4,
                                      unsigned short* __restrict__ F0,
                                      const float* __restrict__ u_feat,
                                      const float* __restrict__ i_feat,
                                      const int* __restrict__ users,
                                      const int* __restrict__ pos,
                                      const int* __restrict__ neg,
                                      float* __restrict__ out)
{
    int bid = blockIdx.x, t = threadIdx.x;
    if (bid < HA) {
        __shared__ int lh[NPART];
        __shared__ int lcur[NPART];
        for (int k = t; k < NPART; k += 256) lh[k] = 0;
        __syncthreads();
        int e0 = (bid * 256 + t) * 8;
        bool act = e0 < N_EDGES;
        int4 u0, u1, i0, i1;
        if (act) {
            u0 = *reinterpret_cast<const int4*>(eu + e0);
            u1 = *reinterpret_cast<const int4*>(eu + e0 + 4);
            i0 = *reinterpret_cast<const int4*>(ei + e0);
            i1 = *reinterpret_cast<const int4*>(ei + e0 + 4);
            atomicAdd(&lh[u0.x >> 10], 1);
            atomicAdd(&lh[u0.y >> 10], 1);
            atomicAdd(&lh[u0.z >> 10], 1);
            atomicAdd(&lh[u0.w >> 10], 1);
            atomicAdd(&lh[u1.x >> 10], 1);
            atomicAdd(&lh[u1.y >> 10], 1);
            atomicAdd(&lh[u1.z >> 10], 1);
            atomicAdd(&lh[u1.w >> 10], 1);
            atomicAdd(&lh[(N_USERS + i0.x) >> 10], 1);
            atomicAdd(&lh[(N_USERS + i0.y) >> 10], 1);
            atomicAdd(&lh[(N_USERS + i0.z) >> 10], 1);
            atomicAdd(&lh[(N_USERS + i0.w) >> 10], 1);
            atomicAdd(&lh[(N_USERS + i1.x) >> 10], 1);
            atomicAdd(&lh[(N_USERS + i1.y) >> 10], 1);
            atomicAdd(&lh[(N_USERS + i1.z) >> 10], 1);
            atomicAdd(&lh[(N_USERS + i1.w) >> 10], 1);
        }
        __syncthreads();
        // reserve: one returning atomic per (block, nonempty partition)
        for (int k = t; k < NPART; k += 256) {
            int v = lh[k];
            lcur[k] = v ? atomicAdd(&gcur[k], v) : 0;
        }
        __syncthreads();
        if (act) {
            float4 wa = *reinterpret_cast<const float4*>(w + e0);
            float4 wb = *reinterpret_cast<const float4*>(w + e0 + 4);
            int us[8] = {u0.x, u0.y, u0.z, u0.w, u1.x, u1.y, u1.z, u1.w};
            int is[8] = {i0.x, i0.y, i0.z, i0.w, i1.x, i1.y, i1.z, i1.w};
            float ws[8] = {wa.x, wa.y, wa.z, wa.w, wb.x, wb.y, wb.z, wb.w};
            #pragma unroll
            for (int j = 0; j < 8; ++j) {
                int bu = us[j];
                int bi = N_USERS + is[j];
                unsigned wbits = __float_as_uint(ws[j]);
                int pu = bu >> 10, pi = bi >> 10;
                int su = atomicAdd(&lcur[pu], 1);      // LDS cursor
                uint2v ru = {(unsigned)(bu & 1023) | ((unsigned)bi << 10), wbits};
                __builtin_nontemporal_store(ru,
                    (uint2v*)&partBuf[(size_t)pu * CAP + su]);
                int si = atomicAdd(&lcur[pi], 1);      // LDS cursor
                uint2v ri = {(unsigned)(bi & 1023) | ((unsigned)bu << 10), wbits};
                __builtin_nontemporal_store(ri,
                    (uint2v*)&partBuf[(size_t)pi * CAP + si]);
            }
        }
    } else if (bid < HA + CB) {
        // f32 -> bf16 convert, 32 floats/thread, 8 loads batched in flight.
        const int NU4 = N_USERS * DIM / 4;           // 3.2M float4s (user side)
        int jb = (bid - HA) * 1024 + t;              // 8-float unit index, round 0
        float4 a[4], b[4];
        #pragma unroll
        for (int c = 0; c < 4; ++c) {
            int j = jb + c * 256;
            if (j < NUNITS) {
                int f4 = j * 2;
                if (f4 < NU4) { a[c] = uf4[f4];       b[c] = uf4[f4 + 1]; }
                else          { a[c] = if4[f4 - NU4]; b[c] = if4[f4 - NU4 + 1]; }
            }
        }
        #pragma unroll
        for (int c = 0; c < 4; ++c) {
            int j = jb + c * 256;
            if (j < NUNITS) {
                uint2 pa = pack4(a[c]), pb = pack4(b[c]);
                uint4v o = {pa.x, pa.y, pb.x, pb.y};
                __builtin_nontemporal_store(o, (uint4v*)(F0 + (size_t)j * 8));
            }
        }
    } else {
        // out = 0.25 * h0 at gathered rows, 8 floats/thread (2 loads in flight)
        int idx = (bid - HA - CB) * 256 + t;         // [0, NOUT*8) exactly
        int row = idx >> 3;
        if (row >= NOUT) return;
        int d8 = (idx & 7) << 3;
        int seg = row >> 13;
        int b = row & (BATCH - 1);
        const float* src;
        if (seg == 0)      src = u_feat + (size_t)users[b] * DIM;
        else if (seg == 1) src = i_feat + (size_t)pos[b]   * DIM;
        else               src = i_feat + (size_t)neg[b]   * DIM;
        float4 v0 = *reinterpret_cast<const float4*>(src + d8);
        float4 v1 = *reinterpret_cast<const float4*>(src + d8 + 4);
        v0.x *= 0.25f; v0.y *= 0.25f; v0.z *= 0.25f; v0.w *= 0.25f;
        v1.x *= 0.25f; v1.y *= 0.25f; v1.z *= 0.25f; v1.w *= 0.25f;
        float* op = out + (size_t)row * DIM + d8;
        *reinterpret_cast<float4*>(op) = v0;
        *reinterpret_cast<float4*>(op + 4) = v1;
    }
}

// ---------------- C: per-partition CSR build (rp2 + entries) ----------------
__global__ void __launch_bounds__(1024)
build_csr_kernel(const int* __restrict__ gcur,
                 const uint2* __restrict__ partBuf,
                 int2* __restrict__ rp2,
                 int2* __restrict__ entries)
{
    __shared__ int h[PLOCAL];
    __shared__ int s[PLOCAL];
    __shared__ int cur[PLOCAL];
    int p = blockIdx.x, t = threadIdx.x;
    int base = p * CAP;
    int end = base + gcur[p];
    h[t] = 0;
    __syncthreads();
    for (int r = base + t; r < end; r += 1024)
        atomicAdd(&h[partBuf[r].x & 1023], 1);
    __syncthreads();
    s[t] = h[t];
    __syncthreads();
    for (int off = 1; off < 1024; off <<= 1) {
        int x = (t >= off) ? s[t - off] : 0;
        __syncthreads();
        s[t] += x;
        __syncthreads();
    }
    int c0 = base + s[t] - h[t];        // exclusive scan -> bucket start (abs)
    cur[t] = c0;
    int gb = p * PLOCAL + t;
    if (gb < NTOT) rp2[gb] = make_int2(c0, h[t]);
    __syncthreads();
    for (int r = base + t; r < end; r += 1024) {
        uint2 rec = partBuf[r];
        int slot = atomicAdd(&cur[rec.x & 1023], 1);   // LDS
        int2v e = {(int)(rec.x >> 10), (int)rec.y};
        __builtin_nontemporal_store(e, (int2v*)&entries[slot]);
    }
}

// ---------------- agg core: branchless masked rounds, 8 lanes/row ----------------
// rp2 = {beg,cnt} -> single dwordx2 at chain head. Masked slots: e={0,0} ->
// row 0, w=0.0 -> exact +0, L1-hot.
__device__ __forceinline__ void agg_row8(int2 rc, int l8, int gb,
                                         const int2* __restrict__ entries,
                                         const unsigned short* __restrict__ src,
                                         float4& sL, float4& sH)
{
    int beg = rc.x, cnt = rc.y;
    float4 a0L = {0,0,0,0}, a0H = {0,0,0,0}, a1L = {0,0,0,0}, a1H = {0,0,0,0};
    for (int base = 0; base < cnt; base += 8) {
        int2 e = make_int2(0, 0);
        if (base + l8 < cnt) e = entries[beg + base + l8];
        int   c[8];
        float wv[8];
        #pragma unroll
        for (int k = 0; k < 8; ++k) {
            c[k]  = __shfl(e.x, gb + k);
            wv[k] = __int_as_float(__shfl(e.y, gb + k));
        }
        uint4 v[8];
        #pragma unroll
        for (int k = 0; k < 8; ++k)
            v[k] = *reinterpret_cast<const uint4*>(
                src + (size_t)c[k] * DIM + l8 * 8);
        #pragma unroll
        for (int k = 0; k < 8; ++k) {
            if (k & 1) {
                fma4(a1L, make_uint2(v[k].x, v[k].y), wv[k]);
                fma4(a1H, make_uint2(v[k].z, v[k].w), wv[k]);
            } else {
                fma4(a0L, make_uint2(v[k].x, v[k].y), wv[k]);
                fma4(a0H, make_uint2(v[k].z, v[k].w), wv[k]);
            }
        }
    }
    sL.x = a0L.x + a1L.x; sL.y = a0L.y + a1L.y;
    sL.z = a0L.z + a1L.z; sL.w = a0L.w + a1L.w;
    sH.x = a0H.x + a1H.x; sH.y = a0H.y + a1H.y;
    sH.z = a0H.z + a1H.z; sH.w = a0H.w + a1H.w;
}

// ---------------- layer 1 (all rows) + flag scatter ----------------
__global__ void agg1_flag_kernel(const int2* __restrict__ rp2,
                                 const int2* __restrict__ entries,
                                 const unsigned short* __restrict__ F0,
                                 unsigned short* __restrict__ H1,
                                 const int* __restrict__ users,
                                 const int* __restrict__ pos,
                                 const int* __restrict__ neg,
                                 int* __restrict__ flags)
{
    int bid = blockIdx.x;
    if (bid < AB8) {
        int gid = bid * 256 + threadIdx.x;
        int lane = gid & 63;
        int l8 = lane & 7;
        int gb = lane & 56;
        int row = gid >> 3;
        if (row >= NTOT) return;
        float4 sL, sH;
        agg_row8(rp2[row], l8, gb, entries, F0, sL, sH);
        uint2 pL = pack4(sL), pH = pack4(sH);
        uint4v o = {pL.x, pL.y, pH.x, pH.y};
        __builtin_nontemporal_store(o, (uint4v*)(H1 + (size_t)row * DIM + l8 * 8));
    } else {
        int t = (bid - AB8) * 256 + threadIdx.x;
        if (t >= NOUT) return;
        int bucket = out_bucket(t, users, pos, neg);
        flags[bucket] = 1;
        int2 rc = rp2[bucket];
        for (int k = rc.x; k < rc.x + rc.y; ++k)
            flags[entries[k].x] = 1;
    }
}

// ---------------- compact flags -> row list ----------------
__global__ void compact_kernel(const int* __restrict__ flags,
                               int* __restrict__ list,
                               int* __restrict__ count)
{
    int t = blockIdx.x * blockDim.x + threadIdx.x;
    int idx = t * 4;
    if (idx >= NTOT) return;
    int4 f = *reinterpret_cast<const int4*>(flags + idx);
    int loc[4]; int k = 0;
    if (f.x) loc[k++] = idx;
    if (f.y) loc[k++] = idx + 1;
    if (f.z) loc[k++] = idx + 2;
    if (f.w) loc[k++] = idx + 3;
    if (k) {
        int base = atomicAdd(count, k);
        for (int m = 0; m < k; ++m) list[base + m] = loc[m];
    }
}

// ---------------- layer 2 (listed rows only) + out += 0.25*H1 ----------------
__global__ void agg2_add1_kernel(const int2* __restrict__ rp2,
                                 const int2* __restrict__ entries,
                                 const unsigned short* __restrict__ H1,
                                 unsigned short* __restrict__ H2,
                                 const int* __restrict__ list,
                                 const int* __restrict__ count,
                                 const int* __restrict__ users,
                                 const int* __restrict__ pos,
                                 const int* __restrict__ neg,
                                 float* __restrict__ out)
{
    int bid = blockIdx.x;
    if (bid < AB8) {
        int gid = bid * 256 + threadIdx.x;
        int lane = gid & 63;
        int l8 = lane & 7;
        int gb = lane & 56;
        int idx = gid >> 3;
        int n = *count;
        if (idx >= n) return;
        int row = list[idx];
        float4 sL, sH;
        agg_row8(rp2[row], l8, gb, entries, H1, sL, sH);
        uint2 pL = pack4(sL), pH = pack4(sH);
        uint4v o = {pL.x, pL.y, pH.x, pH.y};
        __builtin_nontemporal_store(o, (uint4v*)(H2 + (size_t)row * DIM + l8 * 8));
    } else {
        // out += 0.25 * H1[bucket], 8 floats/thread (matches OB = NOUT*8/256)
        int idx = (bid - AB8) * 256 + threadIdx.x;   // [0, NOUT*8)
        int row = idx >> 3;
        if (row >= NOUT) return;
        int d8 = (idx & 7) << 3;
        int bucket = out_bucket(row, users, pos, neg);
        uint4 v = *reinterpret_cast<const uint4*>(H1 + (size_t)bucket * DIM + d8);
        float* op = out + (size_t)row * DIM + d8;
        float4 o0 = *reinterpret_cast<const float4*>(op);
        float4 o1 = *reinterpret_cast<const float4*>(op + 4);
        o0.x += 0.25f * __uint_as_float(v.x << 16);
        o0.y += 0.25f * __uint_as_float(v.x & 0xffff0000u);
        o0.z += 0.25f * __uint_as_float(v.y << 16);
        o0.w += 0.25f * __uint_as_float(v.y & 0xffff0000u);
        o1.x += 0.25f * __uint_as_float(v.z << 16);
        o1.y += 0.25f * __uint_as_float(v.z & 0xffff0000u);
        o1.z += 0.25f * __uint_as_float(v.w << 16);
        o1.w += 0.25f * __uint_as_float(v.w & 0xffff0000u);
        *reinterpret_cast<float4*>(op) = o0;
        *reinterpret_cast<float4*>(op + 4) = o1;
    }
}

// ---------------- layer 3 at output rows, H2 add fused IN-THREAD ----------------
__global__ void aggout_add2_kernel(const int2* __restrict__ rp2,
                                   const int2* __restrict__ entries,
                                   const unsigned short* __restrict__ H2,
                                   const int* __restrict__ users,
                                   const int* __restrict__ pos,
                                   const int* __restrict__ neg,
                                   float* __restrict__ out)
{
    int gid = blockIdx.x * 256 + threadIdx.x;
    int lane = gid & 63;
    int l8 = lane & 7;
    int gb = lane & 56;
    int orow = gid >> 3;
    if (orow >= NOUT) return;
    int bucket = out_bucket(orow, users, pos, neg);
    float4 sL, sH;
    agg_row8(rp2[bucket], l8, gb, entries, H2, sL, sH);
    uint4 v = *reinterpret_cast<const uint4*>(H2 + (size_t)bucket * DIM + l8 * 8);
    sL.x += __uint_as_float(v.x << 16);
    sL.y += __uint_as_float(v.x & 0xffff0000u);
    sL.z += __uint_as_float(v.y << 16);
    sL.w += __uint_as_float(v.y & 0xffff0000u);
    sH.x += __uint_as_float(v.z << 16);
    sH.y += __uint_as_float(v.z & 0xffff0000u);
    sH.z += __uint_as_float(v.w << 16);
    sH.w += __uint_as_float(v.w & 0xffff0000u);
    float* op = out + (size_t)orow * DIM + l8 * 8;
    float4 o0 = *reinterpret_cast<const float4*>(op);
    float4 o1 = *reinterpret_cast<const float4*>(op + 4);
    o0.x += 0.25f * sL.x; o0.y += 0.25f * sL.y;
    o0.z += 0.25f * sL.z; o0.w += 0.25f * sL.w;
    o1.x += 0.25f * sH.x; o1.y += 0.25f * sH.y;
    o1.z += 0.25f * sH.z; o1.w += 0.25f * sH.w;
    *reinterpret_cast<float4*>(op) = o0;
    *reinterpret_cast<float4*>(op + 4) = o1;
}

extern "C" void kernel_launch(void* const* d_in, const int* in_sizes, int n_in,
                              void* d_out, int out_size, void* d_ws, size_t ws_size,
                              hipStream_t stream)
{
    const float* user_feat = (const float*)d_in[0];
    const float* item_feat = (const float*)d_in[1];
    const int*   eu        = (const int*)d_in[2];
    const int*   ei        = (const int*)d_in[3];
    const float* norm      = (const float*)d_in[4];
    const int*   users     = (const int*)d_in[5];
    const int*   pos       = (const int*)d_in[6];
    const int*   neg       = (const int*)d_in[7];
    float* out = (float*)d_out;

    auto align256 = [](size_t x) { return (x + 255) & ~(size_t)255; };
    const size_t hBytes = (size_t)NTOT * DIM * sizeof(unsigned short);  // 38.4 MB
    const size_t pBytes = (size_t)NPART * CAP * 8;                      // 26.4 MB

    char* p = (char*)d_ws;
    unsigned short* F0 = (unsigned short*)p; p += align256(hBytes);
    unsigned short* H1 = (unsigned short*)p; p += align256(hBytes);
    unsigned short* H2 = (unsigned short*)p; p += align256(hBytes);
    // memset region: gcur(512 pad) | flags(NTOT) | count(16 pad)
    int* gcur = (int*)p; p += align256((size_t)(512 + NTOT + 16) * 4);
    int* flags = gcur + 512;
    int* count = flags + NTOT;
    int2* rp2      = (int2*)p;  p += align256((size_t)NTOT * 8);
    uint2* partBuf = (uint2*)p; p += align256(pBytes);
    int*  list     = (int*)p;   p += align256((size_t)NTOT * 4);
    int2* entries  = (int2*)p;  p += align256(pBytes);
    // total ~175 MB

    hipMemsetAsync(gcur, 0, (size_t)(512 + NTOT + 16) * 4, stream);

    // B: partition scatter + f32->bf16 convert + out_h0 (overlapped)
    partition_conv_kernel<<<HA + CB + OB, 256, 0, stream>>>(
        eu, ei, norm, gcur, partBuf,
        (const float4*)user_feat, (const float4*)item_feat, F0,
        user_feat, item_feat, users, pos, neg, out);

    // C: per-partition CSR build (writes rp2 + entries), 1024 thr/block
    build_csr_kernel<<<NPART, 1024, 0, stream>>>(gcur, partBuf, rp2, entries);

    // layer 1 (all rows) + flag scatter for needed-H2 set
    agg1_flag_kernel<<<AB8 + FB, 256, 0, stream>>>(
        rp2, entries, F0, H1, users, pos, neg, flags);

    compact_kernel<<<(NTOT / 4 + 255) / 256, 256, 0, stream>>>(flags, list, count);

    // layer 2 (listed rows) + out += 0.25*H1
    agg2_add1_kernel<<<AB8 + OB, 256, 0, stream>>>(
        rp2, entries, H1, H2, list, count, users, pos, neg, out);

    // layer 3 at output rows with in-thread H2 add
    aggout_add2_kernel<<<NOUT / 32, 256, 0, stream>>>(
        rp2, entries, H2, users, pos, neg, out);
}

// Round 8
// 271.819 us; speedup vs baseline: 1.4665x; 1.4665x over previous
//
#include <hip/hip_runtime.h>

// LightGCN propagation, CSR-gather, bf16 intermediates, unified row space.
// R17 (from R16 FAILED @398us):
//  - Diagnosis: nt-stores on SCATTERED 8B records (partBuf/entries) caused
//    partial-line writeback amplification (WRITE_SIZE 64->112MB, conv 58->102us).
//    ALL nontemporal stores reverted to plain stores.
//  - KEPT from R16 (now cleanly measurable): fixed-capacity partitions
//    (CAP=11264, hist+scan kernels deleted, gcur zero-based) and
//    rp2 = int2{beg,cnt} single-load row headers.

#define N_USERS 200000
#define N_ITEMS 100000
#define N_EDGES 1000000
#define DIM 64
#define BATCH 8192
#define NTOT (N_USERS + N_ITEMS)          // 300000 rows
#define NOUT (3 * BATCH)                  // 24576 output rows
#define NPART 293                         // ceil(NTOT / 1024)
#define PLOCAL 1024
#define CAP 11264                         // per-partition record capacity

#define HA 489                            // scatter blocks: 8 edges/thread
#define NUNITS (NTOT * DIM / 8)           // 2.4M 8-float convert units
#define CB ((NUNITS + 1023) / 1024)       // 2344 convert blocks (32 floats/thread)
#define OB (NOUT * 8 / 256)               // 768 out_h0 / add1 blocks (8 floats/thread)
#define AB8 (NTOT / 32)                   // 9375 agg blocks (32 rows/block, 8 lanes/row)
#define FB ((NOUT + 255) / 256)           // 96 flag-scatter blocks

// ---------- bf16 helpers ----------
__device__ __forceinline__ unsigned f2bf(float f) {   // round-to-nearest-even
    unsigned u = __float_as_uint(f);
    return (u + 0x7fffu + ((u >> 16) & 1u)) >> 16;
}
__device__ __forceinline__ uint2 pack4(float4 v) {
    uint2 o;
    o.x = f2bf(v.x) | (f2bf(v.y) << 16);
    o.y = f2bf(v.z) | (f2bf(v.w) << 16);
    return o;
}
__device__ __forceinline__ void fma4(float4& a, uint2 v, float w) {
    a.x += __uint_as_float(v.x << 16) * w;
    a.y += __uint_as_float(v.x & 0xffff0000u) * w;
    a.z += __uint_as_float(v.y << 16) * w;
    a.w += __uint_as_float(v.y & 0xffff0000u) * w;
}
__device__ __forceinline__ int out_bucket(int orow, const int* users,
                                          const int* pos, const int* neg) {
    int seg = orow >> 13;
    int b = orow & (BATCH - 1);
    if (seg == 0) return users[b];
    if (seg == 1) return N_USERS + pos[b];
    return N_USERS + neg[b];
}

// ---------------- B: partition scatter + convert + out_h0 ----------------
// record meta = (bucket & 1023) | (col << 10);  col < 2^19, total 29 bits.
// gcur[p] is ZERO-based (memset); record address = p*CAP + cursor.
__global__ void partition_conv_kernel(const int* __restrict__ eu,
                                      const int* __restrict__ ei,
                                      const float* __restrict__ w,
                                      int* __restrict__ gcur,
                                      uint2* __restrict__ partBuf,
                                      const float4* __restrict__ uf4,
                                      const float4* __restrict__ if4,
                                      unsigned short* __restrict__ F0,
                                      const float* __restrict__ u_feat,
                                      const float* __restrict__ i_feat,
                                      const int* __restrict__ users,
                                      const int* __restrict__ pos,
                                      const int* __restrict__ neg,
                                      float* __restrict__ out)
{
    int bid = blockIdx.x, t = threadIdx.x;
    if (bid < HA) {
        __shared__ int lh[NPART];
        __shared__ int lcur[NPART];
        for (int k = t; k < NPART; k += 256) lh[k] = 0;
        __syncthreads();
        int e0 = (bid * 256 + t) * 8;
        bool act = e0 < N_EDGES;
        int4 u0, u1, i0, i1;
        if (act) {
            u0 = *reinterpret_cast<const int4*>(eu + e0);
            u1 = *reinterpret_cast<const int4*>(eu + e0 + 4);
            i0 = *reinterpret_cast<const int4*>(ei + e0);
            i1 = *reinterpret_cast<const int4*>(ei + e0 + 4);
            atomicAdd(&lh[u0.x >> 10], 1);
            atomicAdd(&lh[u0.y >> 10], 1);
            atomicAdd(&lh[u0.z >> 10], 1);
            atomicAdd(&lh[u0.w >> 10], 1);
            atomicAdd(&lh[u1.x >> 10], 1);
            atomicAdd(&lh[u1.y >> 10], 1);
            atomicAdd(&lh[u1.z >> 10], 1);
            atomicAdd(&lh[u1.w >> 10], 1);
            atomicAdd(&lh[(N_USERS + i0.x) >> 10], 1);
            atomicAdd(&lh[(N_USERS + i0.y) >> 10], 1);
            atomicAdd(&lh[(N_USERS + i0.z) >> 10], 1);
            atomicAdd(&lh[(N_USERS + i0.w) >> 10], 1);
            atomicAdd(&lh[(N_USERS + i1.x) >> 10], 1);
            atomicAdd(&lh[(N_USERS + i1.y) >> 10], 1);
            atomicAdd(&lh[(N_USERS + i1.z) >> 10], 1);
            atomicAdd(&lh[(N_USERS + i1.w) >> 10], 1);
        }
        __syncthreads();
        // reserve: one returning atomic per (block, nonempty partition)
        for (int k = t; k < NPART; k += 256) {
            int v = lh[k];
            lcur[k] = v ? atomicAdd(&gcur[k], v) : 0;
        }
        __syncthreads();
        if (act) {
            float4 wa = *reinterpret_cast<const float4*>(w + e0);
            float4 wb = *reinterpret_cast<const float4*>(w + e0 + 4);
            int us[8] = {u0.x, u0.y, u0.z, u0.w, u1.x, u1.y, u1.z, u1.w};
            int is[8] = {i0.x, i0.y, i0.z, i0.w, i1.x, i1.y, i1.z, i1.w};
            float ws[8] = {wa.x, wa.y, wa.z, wa.w, wb.x, wb.y, wb.z, wb.w};
            #pragma unroll
            for (int j = 0; j < 8; ++j) {
                int bu = us[j];
                int bi = N_USERS + is[j];
                unsigned wbits = __float_as_uint(ws[j]);
                int pu = bu >> 10, pi = bi >> 10;
                int su = atomicAdd(&lcur[pu], 1);      // LDS cursor
                partBuf[(size_t)pu * CAP + su] =
                    make_uint2((unsigned)(bu & 1023) | ((unsigned)bi << 10), wbits);
                int si = atomicAdd(&lcur[pi], 1);      // LDS cursor
                partBuf[(size_t)pi * CAP + si] =
                    make_uint2((unsigned)(bi & 1023) | ((unsigned)bu << 10), wbits);
            }
        }
    } else if (bid < HA + CB) {
        // f32 -> bf16 convert, 32 floats/thread, 8 loads batched in flight.
        const int NU4 = N_USERS * DIM / 4;           // 3.2M float4s (user side)
        int jb = (bid - HA) * 1024 + t;              // 8-float unit index, round 0
        float4 a[4], b[4];
        #pragma unroll
        for (int c = 0; c < 4; ++c) {
            int j = jb + c * 256;
            if (j < NUNITS) {
                int f4 = j * 2;
                if (f4 < NU4) { a[c] = uf4[f4];       b[c] = uf4[f4 + 1]; }
                else          { a[c] = if4[f4 - NU4]; b[c] = if4[f4 - NU4 + 1]; }
            }
        }
        #pragma unroll
        for (int c = 0; c < 4; ++c) {
            int j = jb + c * 256;
            if (j < NUNITS) {
                uint2 pa = pack4(a[c]), pb = pack4(b[c]);
                *reinterpret_cast<uint4*>(F0 + (size_t)j * 8) =
                    make_uint4(pa.x, pa.y, pb.x, pb.y);
            }
        }
    } else {
        // out = 0.25 * h0 at gathered rows, 8 floats/thread (2 loads in flight)
        int idx = (bid - HA - CB) * 256 + t;         // [0, NOUT*8) exactly
        int row = idx >> 3;
        if (row >= NOUT) return;
        int d8 = (idx & 7) << 3;
        int seg = row >> 13;
        int b = row & (BATCH - 1);
        const float* src;
        if (seg == 0)      src = u_feat + (size_t)users[b] * DIM;
        else if (seg == 1) src = i_feat + (size_t)pos[b]   * DIM;
        else               src = i_feat + (size_t)neg[b]   * DIM;
        float4 v0 = *reinterpret_cast<const float4*>(src + d8);
        float4 v1 = *reinterpret_cast<const float4*>(src + d8 + 4);
        v0.x *= 0.25f; v0.y *= 0.25f; v0.z *= 0.25f; v0.w *= 0.25f;
        v1.x *= 0.25f; v1.y *= 0.25f; v1.z *= 0.25f; v1.w *= 0.25f;
        float* op = out + (size_t)row * DIM + d8;
        *reinterpret_cast<float4*>(op) = v0;
        *reinterpret_cast<float4*>(op + 4) = v1;
    }
}

// ---------------- C: per-partition CSR build (rp2 + entries) ----------------
__global__ void __launch_bounds__(1024)
build_csr_kernel(const int* __restrict__ gcur,
                 const uint2* __restrict__ partBuf,
                 int2* __restrict__ rp2,
                 int2* __restrict__ entries)
{
    __shared__ int h[PLOCAL];
    __shared__ int s[PLOCAL];
    __shared__ int cur[PLOCAL];
    int p = blockIdx.x, t = threadIdx.x;
    int base = p * CAP;
    int end = base + gcur[p];
    h[t] = 0;
    __syncthreads();
    for (int r = base + t; r < end; r += 1024)
        atomicAdd(&h[partBuf[r].x & 1023], 1);
    __syncthreads();
    s[t] = h[t];
    __syncthreads();
    for (int off = 1; off < 1024; off <<= 1) {
        int x = (t >= off) ? s[t - off] : 0;
        __syncthreads();
        s[t] += x;
        __syncthreads();
    }
    int c0 = base + s[t] - h[t];        // exclusive scan -> bucket start (abs)
    cur[t] = c0;
    int gb = p * PLOCAL + t;
    if (gb < NTOT) rp2[gb] = make_int2(c0, h[t]);
    __syncthreads();
    for (int r = base + t; r < end; r += 1024) {
        uint2 rec = partBuf[r];
        int slot = atomicAdd(&cur[rec.x & 1023], 1);   // LDS
        entries[slot] = make_int2((int)(rec.x >> 10), (int)rec.y);
    }
}

// ---------------- agg core: branchless masked rounds, 8 lanes/row ----------------
// rp2 = {beg,cnt} -> single dwordx2 at chain head. Masked slots: e={0,0} ->
// row 0, w=0.0 -> exact +0, L1-hot.
__device__ __forceinline__ void agg_row8(int2 rc, int l8, int gb,
                                         const int2* __restrict__ entries,
                                         const unsigned short* __restrict__ src,
                                         float4& sL, float4& sH)
{
    int beg = rc.x, cnt = rc.y;
    float4 a0L = {0,0,0,0}, a0H = {0,0,0,0}, a1L = {0,0,0,0}, a1H = {0,0,0,0};
    for (int base = 0; base < cnt; base += 8) {
        int2 e = make_int2(0, 0);
        if (base + l8 < cnt) e = entries[beg + base + l8];
        int   c[8];
        float wv[8];
        #pragma unroll
        for (int k = 0; k < 8; ++k) {
            c[k]  = __shfl(e.x, gb + k);
            wv[k] = __int_as_float(__shfl(e.y, gb + k));
        }
        uint4 v[8];
        #pragma unroll
        for (int k = 0; k < 8; ++k)
            v[k] = *reinterpret_cast<const uint4*>(
                src + (size_t)c[k] * DIM + l8 * 8);
        #pragma unroll
        for (int k = 0; k < 8; ++k) {
            if (k & 1) {
                fma4(a1L, make_uint2(v[k].x, v[k].y), wv[k]);
                fma4(a1H, make_uint2(v[k].z, v[k].w), wv[k]);
            } else {
                fma4(a0L, make_uint2(v[k].x, v[k].y), wv[k]);
                fma4(a0H, make_uint2(v[k].z, v[k].w), wv[k]);
            }
        }
    }
    sL.x = a0L.x + a1L.x; sL.y = a0L.y + a1L.y;
    sL.z = a0L.z + a1L.z; sL.w = a0L.w + a1L.w;
    sH.x = a0H.x + a1H.x; sH.y = a0H.y + a1H.y;
    sH.z = a0H.z + a1H.z; sH.w = a0H.w + a1H.w;
}

// ---------------- layer 1 (all rows) + flag scatter ----------------
__global__ void agg1_flag_kernel(const int2* __restrict__ rp2,
                                 const int2* __restrict__ entries,
                                 const unsigned short* __restrict__ F0,
                                 unsigned short* __restrict__ H1,
                                 const int* __restrict__ users,
                                 const int* __restrict__ pos,
                                 const int* __restrict__ neg,
                                 int* __restrict__ flags)
{
    int bid = blockIdx.x;
    if (bid < AB8) {
        int gid = bid * 256 + threadIdx.x;
        int lane = gid & 63;
        int l8 = lane & 7;
        int gb = lane & 56;
        int row = gid >> 3;
        if (row >= NTOT) return;
        float4 sL, sH;
        agg_row8(rp2[row], l8, gb, entries, F0, sL, sH);
        uint2 pL = pack4(sL), pH = pack4(sH);
        *reinterpret_cast<uint4*>(H1 + (size_t)row * DIM + l8 * 8) =
            make_uint4(pL.x, pL.y, pH.x, pH.y);
    } else {
        int t = (bid - AB8) * 256 + threadIdx.x;
        if (t >= NOUT) return;
        int bucket = out_bucket(t, users, pos, neg);
        flags[bucket] = 1;
        int2 rc = rp2[bucket];
        for (int k = rc.x; k < rc.x + rc.y; ++k)
            flags[entries[k].x] = 1;
    }
}

// ---------------- compact flags -> row list ----------------
__global__ void compact_kernel(const int* __restrict__ flags,
                               int* __restrict__ list,
                               int* __restrict__ count)
{
    int t = blockIdx.x * blockDim.x + threadIdx.x;
    int idx = t * 4;
    if (idx >= NTOT) return;
    int4 f = *reinterpret_cast<const int4*>(flags + idx);
    int loc[4]; int k = 0;
    if (f.x) loc[k++] = idx;
    if (f.y) loc[k++] = idx + 1;
    if (f.z) loc[k++] = idx + 2;
    if (f.w) loc[k++] = idx + 3;
    if (k) {
        int base = atomicAdd(count, k);
        for (int m = 0; m < k; ++m) list[base + m] = loc[m];
    }
}

// ---------------- layer 2 (listed rows only) + out += 0.25*H1 ----------------
__global__ void agg2_add1_kernel(const int2* __restrict__ rp2,
                                 const int2* __restrict__ entries,
                                 const unsigned short* __restrict__ H1,
                                 unsigned short* __restrict__ H2,
                                 const int* __restrict__ list,
                                 const int* __restrict__ count,
                                 const int* __restrict__ users,
                                 const int* __restrict__ pos,
                                 const int* __restrict__ neg,
                                 float* __restrict__ out)
{
    int bid = blockIdx.x;
    if (bid < AB8) {
        int gid = bid * 256 + threadIdx.x;
        int lane = gid & 63;
        int l8 = lane & 7;
        int gb = lane & 56;
        int idx = gid >> 3;
        int n = *count;
        if (idx >= n) return;
        int row = list[idx];
        float4 sL, sH;
        agg_row8(rp2[row], l8, gb, entries, H1, sL, sH);
        uint2 pL = pack4(sL), pH = pack4(sH);
        *reinterpret_cast<uint4*>(H2 + (size_t)row * DIM + l8 * 8) =
            make_uint4(pL.x, pL.y, pH.x, pH.y);
    } else {
        // out += 0.25 * H1[bucket], 8 floats/thread (matches OB = NOUT*8/256)
        int idx = (bid - AB8) * 256 + threadIdx.x;   // [0, NOUT*8)
        int row = idx >> 3;
        if (row >= NOUT) return;
        int d8 = (idx & 7) << 3;
        int bucket = out_bucket(row, users, pos, neg);
        uint4 v = *reinterpret_cast<const uint4*>(H1 + (size_t)bucket * DIM + d8);
        float* op = out + (size_t)row * DIM + d8;
        float4 o0 = *reinterpret_cast<const float4*>(op);
        float4 o1 = *reinterpret_cast<const float4*>(op + 4);
        o0.x += 0.25f * __uint_as_float(v.x << 16);
        o0.y += 0.25f * __uint_as_float(v.x & 0xffff0000u);
        o0.z += 0.25f * __uint_as_float(v.y << 16);
        o0.w += 0.25f * __uint_as_float(v.y & 0xffff0000u);
        o1.x += 0.25f * __uint_as_float(v.z << 16);
        o1.y += 0.25f * __uint_as_float(v.z & 0xffff0000u);
        o1.z += 0.25f * __uint_as_float(v.w << 16);
        o1.w += 0.25f * __uint_as_float(v.w & 0xffff0000u);
        *reinterpret_cast<float4*>(op) = o0;
        *reinterpret_cast<float4*>(op + 4) = o1;
    }
}

// ---------------- layer 3 at output rows, H2 add fused IN-THREAD ----------------
__global__ void aggout_add2_kernel(const int2* __restrict__ rp2,
                                   const int2* __restrict__ entries,
                                   const unsigned short* __restrict__ H2,
                                   const int* __restrict__ users,
                                   const int* __restrict__ pos,
                                   const int* __restrict__ neg,
                                   float* __restrict__ out)
{
    int gid = blockIdx.x * 256 + threadIdx.x;
    int lane = gid & 63;
    int l8 = lane & 7;
    int gb = lane & 56;
    int orow = gid >> 3;
    if (orow >= NOUT) return;
    int bucket = out_bucket(orow, users, pos, neg);
    float4 sL, sH;
    agg_row8(rp2[bucket], l8, gb, entries, H2, sL, sH);
    uint4 v = *reinterpret_cast<const uint4*>(H2 + (size_t)bucket * DIM + l8 * 8);
    sL.x += __uint_as_float(v.x << 16);
    sL.y += __uint_as_float(v.x & 0xffff0000u);
    sL.z += __uint_as_float(v.y << 16);
    sL.w += __uint_as_float(v.y & 0xffff0000u);
    sH.x += __uint_as_float(v.z << 16);
    sH.y += __uint_as_float(v.z & 0xffff0000u);
    sH.z += __uint_as_float(v.w << 16);
    sH.w += __uint_as_float(v.w & 0xffff0000u);
    float* op = out + (size_t)orow * DIM + l8 * 8;
    float4 o0 = *reinterpret_cast<const float4*>(op);
    float4 o1 = *reinterpret_cast<const float4*>(op + 4);
    o0.x += 0.25f * sL.x; o0.y += 0.25f * sL.y;
    o0.z += 0.25f * sL.z; o0.w += 0.25f * sL.w;
    o1.x += 0.25f * sH.x; o1.y += 0.25f * sH.y;
    o1.z += 0.25f * sH.z; o1.w += 0.25f * sH.w;
    *reinterpret_cast<float4*>(op) = o0;
    *reinterpret_cast<float4*>(op + 4) = o1;
}

extern "C" void kernel_launch(void* const* d_in, const int* in_sizes, int n_in,
                              void* d_out, int out_size, void* d_ws, size_t ws_size,
                              hipStream_t stream)
{
    const float* user_feat = (const float*)d_in[0];
    const float* item_feat = (const float*)d_in[1];
    const int*   eu        = (const int*)d_in[2];
    const int*   ei        = (const int*)d_in[3];
    const float* norm      = (const float*)d_in[4];
    const int*   users     = (const int*)d_in[5];
    const int*   pos       = (const int*)d_in[6];
    const int*   neg       = (const int*)d_in[7];
    float* out = (float*)d_out;

    auto align256 = [](size_t x) { return (x + 255) & ~(size_t)255; };
    const size_t hBytes = (size_t)NTOT * DIM * sizeof(unsigned short);  // 38.4 MB
    const size_t pBytes = (size_t)NPART * CAP * 8;                      // 26.4 MB

    char* p = (char*)d_ws;
    unsigned short* F0 = (unsigned short*)p; p += align256(hBytes);
    unsigned short* H1 = (unsigned short*)p; p += align256(hBytes);
    unsigned short* H2 = (unsigned short*)p; p += align256(hBytes);
    // memset region: gcur(512 pad) | flags(NTOT) | count(16 pad)
    int* gcur = (int*)p; p += align256((size_t)(512 + NTOT + 16) * 4);
    int* flags = gcur + 512;
    int* count = flags + NTOT;
    int2* rp2      = (int2*)p;  p += align256((size_t)NTOT * 8);
    uint2* partBuf = (uint2*)p; p += align256(pBytes);
    int*  list     = (int*)p;   p += align256((size_t)NTOT * 4);
    int2* entries  = (int2*)p;  p += align256(pBytes);
    // total ~175 MB

    hipMemsetAsync(gcur, 0, (size_t)(512 + NTOT + 16) * 4, stream);

    // B: partition scatter + f32->bf16 convert + out_h0 (overlapped)
    partition_conv_kernel<<<HA + CB + OB, 256, 0, stream>>>(
        eu, ei, norm, gcur, partBuf,
        (const float4*)user_feat, (const float4*)item_feat, F0,
        user_feat, item_feat, users, pos, neg, out);

    // C: per-partition CSR build (writes rp2 + entries), 1024 thr/block
    build_csr_kernel<<<NPART, 1024, 0, stream>>>(gcur, partBuf, rp2, entries);

    // layer 1 (all rows) + flag scatter for needed-H2 set
    agg1_flag_kernel<<<AB8 + FB, 256, 0, stream>>>(
        rp2, entries, F0, H1, users, pos, neg, flags);

    compact_kernel<<<(NTOT / 4 + 255) / 256, 256, 0, stream>>>(flags, list, count);

    // layer 2 (listed rows) + out += 0.25*H1
    agg2_add1_kernel<<<AB8 + OB, 256, 0, stream>>>(
        rp2, entries, H1, H2, list, count, users, pos, neg, out);

    // layer 3 at output rows with in-thread H2 add
    aggout_add2_kernel<<<NOUT / 32, 256, 0, stream>>>(
        rp2, entries, H2, users, pos, neg, out);
}

// Round 9
// 267.170 us; speedup vs baseline: 1.4920x; 1.0174x over previous
//
#include <hip/hip_runtime.h>

// LightGCN propagation, CSR-gather, bf16 intermediates, unified row space.
// R18 (from R17 @271.8us):
//  - Serial-chain restructure. Old: conv(scatter+convert) -> csr -> agg1+flag
//    -> compact -> agg2. The convert (~33us streaming) serialized before csr
//    (293 blocks, 80% GPU idle), and flag+compact sat after agg1.
//  - New: prep(isOut bitmap + out_h0) -> scatter(+flags direct from edges via
//    isOut) -> mid{csr || convert || compact in ONE 1024-thr launch} ->
//    agg1(gather only) -> agg2 -> aggout.
//    flags[neighbor] from edge (u,i): isOut[u] -> flags[N+i]=1 and vice versa
//    == old per-bucket entry walk, but needs no CSR.
//  - agg core / agg2 / aggout unchanged from R17.

#define N_USERS 200000
#define N_ITEMS 100000
#define N_EDGES 1000000
#define DIM 64
#define BATCH 8192
#define NTOT (N_USERS + N_ITEMS)          // 300000 rows
#define NOUT (3 * BATCH)                  // 24576 output rows
#define NPART 293                         // ceil(NTOT / 1024)
#define PLOCAL 1024
#define CAP 11264                         // per-partition record capacity

#define HA 489                            // scatter blocks: 8 edges/thread
#define NUNITS (NTOT * DIM / 8)           // 2.4M 8-float convert units
#define OB (NOUT * 8 / 256)               // 768 add1 blocks (8 floats/thread)
#define AB8 (NTOT / 32)                   // 9375 agg blocks (32 rows/block)
// prep launch (1024 thr): isOut blocks + out_h0 blocks
#define PRB (NOUT / 1024)                 // 24 isOut blocks
#define PHB (NOUT * 8 / 1024)             // 192 out_h0 blocks
// mid launch (1024 thr): csr | convert | compact
#define CVB ((NUNITS + 4095) / 4096)      // 586 convert blocks (32 floats/thread)
#define CPB ((NTOT / 4 + 1023) / 1024)    // 74 compact blocks

// ---------- bf16 helpers ----------
__device__ __forceinline__ unsigned f2bf(float f) {   // round-to-nearest-even
    unsigned u = __float_as_uint(f);
    return (u + 0x7fffu + ((u >> 16) & 1u)) >> 16;
}
__device__ __forceinline__ uint2 pack4(float4 v) {
    uint2 o;
    o.x = f2bf(v.x) | (f2bf(v.y) << 16);
    o.y = f2bf(v.z) | (f2bf(v.w) << 16);
    return o;
}
__device__ __forceinline__ void fma4(float4& a, uint2 v, float w) {
    a.x += __uint_as_float(v.x << 16) * w;
    a.y += __uint_as_float(v.x & 0xffff0000u) * w;
    a.z += __uint_as_float(v.y << 16) * w;
    a.w += __uint_as_float(v.y & 0xffff0000u) * w;
}
__device__ __forceinline__ int out_bucket(int orow, const int* users,
                                          const int* pos, const int* neg) {
    int seg = orow >> 13;
    int b = orow & (BATCH - 1);
    if (seg == 0) return users[b];
    if (seg == 1) return N_USERS + pos[b];
    return N_USERS + neg[b];
}

// ---------------- P: isOut bitmap + flags[bucket] + out_h0 ----------------
__global__ void __launch_bounds__(1024)
prep_kernel(const int* __restrict__ users,
            const int* __restrict__ pos,
            const int* __restrict__ neg,
            const float* __restrict__ u_feat,
            const float* __restrict__ i_feat,
            unsigned char* __restrict__ isOut,
            int* __restrict__ flags,
            float* __restrict__ out)
{
    int bid = blockIdx.x, t = threadIdx.x;
    if (bid < PRB) {
        int orow = bid * 1024 + t;                   // [0, NOUT) exactly
        int bucket = out_bucket(orow, users, pos, neg);
        isOut[bucket] = 1;
        flags[bucket] = 1;
    } else {
        // out = 0.25 * h0 at gathered rows, 8 floats/thread
        int idx = (bid - PRB) * 1024 + t;            // [0, NOUT*8) exactly
        int row = idx >> 3;
        int d8 = (idx & 7) << 3;
        int seg = row >> 13;
        int b = row & (BATCH - 1);
        const float* src;
        if (seg == 0)      src = u_feat + (size_t)users[b] * DIM;
        else if (seg == 1) src = i_feat + (size_t)pos[b]   * DIM;
        else               src = i_feat + (size_t)neg[b]   * DIM;
        float4 v0 = *reinterpret_cast<const float4*>(src + d8);
        float4 v1 = *reinterpret_cast<const float4*>(src + d8 + 4);
        v0.x *= 0.25f; v0.y *= 0.25f; v0.z *= 0.25f; v0.w *= 0.25f;
        v1.x *= 0.25f; v1.y *= 0.25f; v1.z *= 0.25f; v1.w *= 0.25f;
        float* op = out + (size_t)row * DIM + d8;
        *reinterpret_cast<float4*>(op) = v0;
        *reinterpret_cast<float4*>(op + 4) = v1;
    }
}

// ---------------- B: partition scatter + edge-based flag scatter ----------------
// record meta = (bucket & 1023) | (col << 10);  col < 2^19, total 29 bits.
// gcur[p] is ZERO-based (memset); record address = p*CAP + cursor.
__global__ void scatter_kernel(const int* __restrict__ eu,
                               const int* __restrict__ ei,
                               const float* __restrict__ w,
                               int* __restrict__ gcur,
                               uint2* __restrict__ partBuf,
                               const unsigned char* __restrict__ isOut,
                               int* __restrict__ flags)
{
    __shared__ int lh[NPART];
    __shared__ int lcur[NPART];
    int bid = blockIdx.x, t = threadIdx.x;
    for (int k = t; k < NPART; k += 256) lh[k] = 0;
    __syncthreads();
    int e0 = (bid * 256 + t) * 8;
    bool act = e0 < N_EDGES;
    int4 u0, u1, i0, i1;
    if (act) {
        u0 = *reinterpret_cast<const int4*>(eu + e0);
        u1 = *reinterpret_cast<const int4*>(eu + e0 + 4);
        i0 = *reinterpret_cast<const int4*>(ei + e0);
        i1 = *reinterpret_cast<const int4*>(ei + e0 + 4);
        atomicAdd(&lh[u0.x >> 10], 1);
        atomicAdd(&lh[u0.y >> 10], 1);
        atomicAdd(&lh[u0.z >> 10], 1);
        atomicAdd(&lh[u0.w >> 10], 1);
        atomicAdd(&lh[u1.x >> 10], 1);
        atomicAdd(&lh[u1.y >> 10], 1);
        atomicAdd(&lh[u1.z >> 10], 1);
        atomicAdd(&lh[u1.w >> 10], 1);
        atomicAdd(&lh[(N_USERS + i0.x) >> 10], 1);
        atomicAdd(&lh[(N_USERS + i0.y) >> 10], 1);
        atomicAdd(&lh[(N_USERS + i0.z) >> 10], 1);
        atomicAdd(&lh[(N_USERS + i0.w) >> 10], 1);
        atomicAdd(&lh[(N_USERS + i1.x) >> 10], 1);
        atomicAdd(&lh[(N_USERS + i1.y) >> 10], 1);
        atomicAdd(&lh[(N_USERS + i1.z) >> 10], 1);
        atomicAdd(&lh[(N_USERS + i1.w) >> 10], 1);
    }
    __syncthreads();
    // reserve: one returning atomic per (block, nonempty partition)
    for (int k = t; k < NPART; k += 256) {
        int v = lh[k];
        lcur[k] = v ? atomicAdd(&gcur[k], v) : 0;
    }
    __syncthreads();
    if (act) {
        float4 wa = *reinterpret_cast<const float4*>(w + e0);
        float4 wb = *reinterpret_cast<const float4*>(w + e0 + 4);
        int us[8] = {u0.x, u0.y, u0.z, u0.w, u1.x, u1.y, u1.z, u1.w};
        int is[8] = {i0.x, i0.y, i0.z, i0.w, i1.x, i1.y, i1.z, i1.w};
        float ws[8] = {wa.x, wa.y, wa.z, wa.w, wb.x, wb.y, wb.z, wb.w};
        #pragma unroll
        for (int j = 0; j < 8; ++j) {
            int bu = us[j];
            int bi = N_USERS + is[j];
            unsigned wbits = __float_as_uint(ws[j]);
            int pu = bu >> 10, pi = bi >> 10;
            int su = atomicAdd(&lcur[pu], 1);      // LDS cursor
            partBuf[(size_t)pu * CAP + su] =
                make_uint2((unsigned)(bu & 1023) | ((unsigned)bi << 10), wbits);
            int si = atomicAdd(&lcur[pi], 1);      // LDS cursor
            partBuf[(size_t)pi * CAP + si] =
                make_uint2((unsigned)(bi & 1023) | ((unsigned)bu << 10), wbits);
            // flags for H2-needed rows, straight from the edge
            if (isOut[bu]) flags[bi] = 1;
            if (isOut[bi]) flags[bu] = 1;
        }
    }
}

// ---------------- M: csr | convert | compact (one wide launch) ----------------
__global__ void __launch_bounds__(1024)
mid_kernel(const int* __restrict__ gcur,
           const uint2* __restrict__ partBuf,
           int2* __restrict__ rp2,
           int2* __restrict__ entries,
           const float4* __restrict__ uf4,
           const float4* __restrict__ if4,
           unsigned short* __restrict__ F0,
           const int* __restrict__ flags,
           int* __restrict__ list,
           int* __restrict__ count)
{
    __shared__ int h[PLOCAL];
    __shared__ int s[PLOCAL];
    __shared__ int cur[PLOCAL];
    int bid = blockIdx.x, t = threadIdx.x;
    if (bid < NPART) {
        // ---- per-partition CSR build ----
        int p = bid;
        int base = p * CAP;
        int end = base + gcur[p];
        h[t] = 0;
        __syncthreads();
        for (int r = base + t; r < end; r += 1024)
            atomicAdd(&h[partBuf[r].x & 1023], 1);
        __syncthreads();
        s[t] = h[t];
        __syncthreads();
        for (int off = 1; off < 1024; off <<= 1) {
            int x = (t >= off) ? s[t - off] : 0;
            __syncthreads();
            s[t] += x;
            __syncthreads();
        }
        int c0 = base + s[t] - h[t];    // exclusive scan -> bucket start (abs)
        cur[t] = c0;
        int gb = p * PLOCAL + t;
        if (gb < NTOT) rp2[gb] = make_int2(c0, h[t]);
        __syncthreads();
        for (int r = base + t; r < end; r += 1024) {
            uint2 rec = partBuf[r];
            int slot = atomicAdd(&cur[rec.x & 1023], 1);   // LDS
            entries[slot] = make_int2((int)(rec.x >> 10), (int)rec.y);
        }
    } else if (bid < NPART + CVB) {
        // ---- f32 -> bf16 convert, 32 floats/thread, 8 loads in flight ----
        const int NU4 = N_USERS * DIM / 4;           // 3.2M float4s (user side)
        int jb = (bid - NPART) * 4096 + t;           // 8-float unit index
        float4 a[4], b[4];
        #pragma unroll
        for (int c = 0; c < 4; ++c) {
            int j = jb + c * 1024;
            if (j < NUNITS) {
                int f4 = j * 2;
                if (f4 < NU4) { a[c] = uf4[f4];       b[c] = uf4[f4 + 1]; }
                else          { a[c] = if4[f4 - NU4]; b[c] = if4[f4 - NU4 + 1]; }
            }
        }
        #pragma unroll
        for (int c = 0; c < 4; ++c) {
            int j = jb + c * 1024;
            if (j < NUNITS) {
                uint2 pa = pack4(a[c]), pb = pack4(b[c]);
                *reinterpret_cast<uint4*>(F0 + (size_t)j * 8) =
                    make_uint4(pa.x, pa.y, pb.x, pb.y);
            }
        }
    } else {
        // ---- compact flags -> row list ----
        int idx = ((bid - NPART - CVB) * 1024 + t) * 4;
        if (idx >= NTOT) return;
        int4 f = *reinterpret_cast<const int4*>(flags + idx);
        int loc[4]; int k = 0;
        if (f.x) loc[k++] = idx;
        if (f.y) loc[k++] = idx + 1;
        if (f.z) loc[k++] = idx + 2;
        if (f.w) loc[k++] = idx + 3;
        if (k) {
            int base = atomicAdd(count, k);
            for (int m = 0; m < k; ++m) list[base + m] = loc[m];
        }
    }
}

// ---------------- agg core: branchless masked rounds, 8 lanes/row ----------------
// rp2 = {beg,cnt} -> single dwordx2 at chain head. Masked slots: e={0,0} ->
// row 0, w=0.0 -> exact +0, L1-hot.
__device__ __forceinline__ void agg_row8(int2 rc, int l8, int gb,
                                         const int2* __restrict__ entries,
                                         const unsigned short* __restrict__ src,
                                         float4& sL, float4& sH)
{
    int beg = rc.x, cnt = rc.y;
    float4 a0L = {0,0,0,0}, a0H = {0,0,0,0}, a1L = {0,0,0,0}, a1H = {0,0,0,0};
    for (int base = 0; base < cnt; base += 8) {
        int2 e = make_int2(0, 0);
        if (base + l8 < cnt) e = entries[beg + base + l8];
        int   c[8];
        float wv[8];
        #pragma unroll
        for (int k = 0; k < 8; ++k) {
            c[k]  = __shfl(e.x, gb + k);
            wv[k] = __int_as_float(__shfl(e.y, gb + k));
        }
        uint4 v[8];
        #pragma unroll
        for (int k = 0; k < 8; ++k)
            v[k] = *reinterpret_cast<const uint4*>(
                src + (size_t)c[k] * DIM + l8 * 8);
        #pragma unroll
        for (int k = 0; k < 8; ++k) {
            if (k & 1) {
                fma4(a1L, make_uint2(v[k].x, v[k].y), wv[k]);
                fma4(a1H, make_uint2(v[k].z, v[k].w), wv[k]);
            } else {
                fma4(a0L, make_uint2(v[k].x, v[k].y), wv[k]);
                fma4(a0H, make_uint2(v[k].z, v[k].w), wv[k]);
            }
        }
    }
    sL.x = a0L.x + a1L.x; sL.y = a0L.y + a1L.y;
    sL.z = a0L.z + a1L.z; sL.w = a0L.w + a1L.w;
    sH.x = a0H.x + a1H.x; sH.y = a0H.y + a1H.y;
    sH.z = a0H.z + a1H.z; sH.w = a0H.w + a1H.w;
}

// ---------------- layer 1 (all rows, gather only) ----------------
__global__ void agg1_kernel(const int2* __restrict__ rp2,
                            const int2* __restrict__ entries,
                            const unsigned short* __restrict__ F0,
                            unsigned short* __restrict__ H1)
{
    int gid = blockIdx.x * 256 + threadIdx.x;
    int lane = gid & 63;
    int l8 = lane & 7;
    int gb = lane & 56;
    int row = gid >> 3;
    if (row >= NTOT) return;
    float4 sL, sH;
    agg_row8(rp2[row], l8, gb, entries, F0, sL, sH);
    uint2 pL = pack4(sL), pH = pack4(sH);
    *reinterpret_cast<uint4*>(H1 + (size_t)row * DIM + l8 * 8) =
        make_uint4(pL.x, pL.y, pH.x, pH.y);
}

// ---------------- layer 2 (listed rows only) + out += 0.25*H1 ----------------
__global__ void agg2_add1_kernel(const int2* __restrict__ rp2,
                                 const int2* __restrict__ entries,
                                 const unsigned short* __restrict__ H1,
                                 unsigned short* __restrict__ H2,
                                 const int* __restrict__ list,
                                 const int* __restrict__ count,
                                 const int* __restrict__ users,
                                 const int* __restrict__ pos,
                                 const int* __restrict__ neg,
                                 float* __restrict__ out)
{
    int bid = blockIdx.x;
    if (bid < AB8) {
        int gid = bid * 256 + threadIdx.x;
        int lane = gid & 63;
        int l8 = lane & 7;
        int gb = lane & 56;
        int idx = gid >> 3;
        int n = *count;
        if (idx >= n) return;
        int row = list[idx];
        float4 sL, sH;
        agg_row8(rp2[row], l8, gb, entries, H1, sL, sH);
        uint2 pL = pack4(sL), pH = pack4(sH);
        *reinterpret_cast<uint4*>(H2 + (size_t)row * DIM + l8 * 8) =
            make_uint4(pL.x, pL.y, pH.x, pH.y);
    } else {
        // out += 0.25 * H1[bucket], 8 floats/thread (matches OB = NOUT*8/256)
        int idx = (bid - AB8) * 256 + threadIdx.x;   // [0, NOUT*8)
        int row = idx >> 3;
        if (row >= NOUT) return;
        int d8 = (idx & 7) << 3;
        int bucket = out_bucket(row, users, pos, neg);
        uint4 v = *reinterpret_cast<const uint4*>(H1 + (size_t)bucket * DIM + d8);
        float* op = out + (size_t)row * DIM + d8;
        float4 o0 = *reinterpret_cast<const float4*>(op);
        float4 o1 = *reinterpret_cast<const float4*>(op + 4);
        o0.x += 0.25f * __uint_as_float(v.x << 16);
        o0.y += 0.25f * __uint_as_float(v.x & 0xffff0000u);
        o0.z += 0.25f * __uint_as_float(v.y << 16);
        o0.w += 0.25f * __uint_as_float(v.y & 0xffff0000u);
        o1.x += 0.25f * __uint_as_float(v.z << 16);
        o1.y += 0.25f * __uint_as_float(v.z & 0xffff0000u);
        o1.z += 0.25f * __uint_as_float(v.w << 16);
        o1.w += 0.25f * __uint_as_float(v.w & 0xffff0000u);
        *reinterpret_cast<float4*>(op) = o0;
        *reinterpret_cast<float4*>(op + 4) = o1;
    }
}

// ---------------- layer 3 at output rows, H2 add fused IN-THREAD ----------------
__global__ void aggout_add2_kernel(const int2* __restrict__ rp2,
                                   const int2* __restrict__ entries,
                                   const unsigned short* __restrict__ H2,
                                   const int* __restrict__ users,
                                   const int* __restrict__ pos,
                                   const int* __restrict__ neg,
                                   float* __restrict__ out)
{
    int gid = blockIdx.x * 256 + threadIdx.x;
    int lane = gid & 63;
    int l8 = lane & 7;
    int gb = lane & 56;
    int orow = gid >> 3;
    if (orow >= NOUT) return;
    int bucket = out_bucket(orow, users, pos, neg);
    float4 sL, sH;
    agg_row8(rp2[bucket], l8, gb, entries, H2, sL, sH);
    uint4 v = *reinterpret_cast<const uint4*>(H2 + (size_t)bucket * DIM + l8 * 8);
    sL.x += __uint_as_float(v.x << 16);
    sL.y += __uint_as_float(v.x & 0xffff0000u);
    sL.z += __uint_as_float(v.y << 16);
    sL.w += __uint_as_float(v.y & 0xffff0000u);
    sH.x += __uint_as_float(v.z << 16);
    sH.y += __uint_as_float(v.z & 0xffff0000u);
    sH.z += __uint_as_float(v.w << 16);
    sH.w += __uint_as_float(v.w & 0xffff0000u);
    float* op = out + (size_t)orow * DIM + l8 * 8;
    float4 o0 = *reinterpret_cast<const float4*>(op);
    float4 o1 = *reinterpret_cast<const float4*>(op + 4);
    o0.x += 0.25f * sL.x; o0.y += 0.25f * sL.y;
    o0.z += 0.25f * sL.z; o0.w += 0.25f * sL.w;
    o1.x += 0.25f * sH.x; o1.y += 0.25f * sH.y;
    o1.z += 0.25f * sH.z; o1.w += 0.25f * sH.w;
    *reinterpret_cast<float4*>(op) = o0;
    *reinterpret_cast<float4*>(op + 4) = o1;
}

extern "C" void kernel_launch(void* const* d_in, const int* in_sizes, int n_in,
                              void* d_out, int out_size, void* d_ws, size_t ws_size,
                              hipStream_t stream)
{
    const float* user_feat = (const float*)d_in[0];
    const float* item_feat = (const float*)d_in[1];
    const int*   eu        = (const int*)d_in[2];
    const int*   ei        = (const int*)d_in[3];
    const float* norm      = (const float*)d_in[4];
    const int*   users     = (const int*)d_in[5];
    const int*   pos       = (const int*)d_in[6];
    const int*   neg       = (const int*)d_in[7];
    float* out = (float*)d_out;

    auto align256 = [](size_t x) { return (x + 255) & ~(size_t)255; };
    const size_t hBytes = (size_t)NTOT * DIM * sizeof(unsigned short);  // 38.4 MB
    const size_t pBytes = (size_t)NPART * CAP * 8;                      // 26.4 MB

    char* p = (char*)d_ws;
    unsigned short* F0 = (unsigned short*)p; p += align256(hBytes);
    unsigned short* H1 = (unsigned short*)p; p += align256(hBytes);
    unsigned short* H2 = (unsigned short*)p; p += align256(hBytes);
    // memset region: gcur(512 pad) | flags(NTOT) | count(16 pad) | isOut(NTOT B)
    const size_t zBytes = (size_t)(512 + NTOT + 16) * 4 + NTOT;
    int* gcur = (int*)p;
    int* flags = gcur + 512;
    int* count = flags + NTOT;
    unsigned char* isOut = (unsigned char*)(count + 16);
    p += align256(zBytes);
    int2* rp2      = (int2*)p;  p += align256((size_t)NTOT * 8);
    uint2* partBuf = (uint2*)p; p += align256(pBytes);
    int*  list     = (int*)p;   p += align256((size_t)NTOT * 4);
    int2* entries  = (int2*)p;  p += align256(pBytes);
    // total ~175 MB

    hipMemsetAsync(gcur, 0, zBytes, stream);

    // P: isOut bitmap + flags[bucket] + out_h0
    prep_kernel<<<PRB + PHB, 1024, 0, stream>>>(
        users, pos, neg, user_feat, item_feat, isOut, flags, out);

    // B: partition scatter + edge-based flag scatter
    scatter_kernel<<<HA, 256, 0, stream>>>(
        eu, ei, norm, gcur, partBuf, isOut, flags);

    // M: csr || convert || compact (one wide launch; all deps from B or inputs)
    mid_kernel<<<NPART + CVB + CPB, 1024, 0, stream>>>(
        gcur, partBuf, rp2, entries,
        (const float4*)user_feat, (const float4*)item_feat, F0,
        flags, list, count);

    // layer 1 (all rows, gather only)
    agg1_kernel<<<AB8, 256, 0, stream>>>(rp2, entries, F0, H1);

    // layer 2 (listed rows) + out += 0.25*H1
    agg2_add1_kernel<<<AB8 + OB, 256, 0, stream>>>(
        rp2, entries, H1, H2, list, count, users, pos, neg, out);

    // layer 3 at output rows with in-thread H2 add
    aggout_add2_kernel<<<NOUT / 32, 256, 0, stream>>>(
        rp2, entries, H2, users, pos, neg, out);
}